// Round 9
// baseline (677.206 us; speedup 1.0000x reference)
//
#include <hip/hip_runtime.h>

// MultiHeadAttention: B=4 S=2048 D=1024 H=16 DK=64
// outputs: [out (B,S,D) fp32 ; attn (B,H,S,S) fp32]
#define B_ 4
#define S_ 2048
#define D_ 1024
#define H_ 16
#define DK_ 64
#define M_ (B_ * S_) /* 8192 */

typedef __attribute__((ext_vector_type(8))) _Float16 f16x8;
typedef __attribute__((ext_vector_type(4))) _Float16 f16x4;
typedef __attribute__((ext_vector_type(4))) float f32x4;

#define QSCALE 0.18033688011113607f /* 0.125 * log2(e) */

__device__ __forceinline__ f32x4 mfma16(f16x8 a, f16x8 b, f32x4 c) {
  return __builtin_amdgcn_mfma_f32_16x16x32_f16(a, b, c, 0, 0, 0);
}

// async global->LDS, 16B per lane; LDS dest is wave-uniform base + lane*16
__device__ __forceinline__ void gl2lds(const _Float16* g, _Float16* l) {
  __builtin_amdgcn_global_load_lds(
      (const __attribute__((address_space(1))) void*)g,
      (__attribute__((address_space(3))) void*)l, 16, 0, 0);
}

// ---------------- fp32 -> f16 for the 4 weight matrices ----------------
#define NW8 (D_ * D_ / 8) /* 131072 = 1<<17 */
__global__ __launch_bounds__(256) void cvt_w(
    const float* __restrict__ wq, const float* __restrict__ wk,
    const float* __restrict__ wv, const float* __restrict__ wo,
    _Float16* __restrict__ wqh, _Float16* __restrict__ wkh,
    _Float16* __restrict__ wvh, _Float16* __restrict__ woh) {
  const int i = blockIdx.x * 256 + threadIdx.x;
  const int t = i >> 17;
  const int off = i & (NW8 - 1);
  const float* src = t == 0 ? wq : (t == 1 ? wk : (t == 2 ? wv : wo));
  _Float16* dst = t == 0 ? wqh : (t == 1 ? wkh : (t == 2 ? wvh : woh));
  const f32x4 a = *reinterpret_cast<const f32x4*>(&src[(size_t)off * 8]);
  const f32x4 b = *reinterpret_cast<const f32x4*>(&src[(size_t)off * 8 + 4]);
  f16x8 h;
  h[0] = (_Float16)a[0]; h[1] = (_Float16)a[1]; h[2] = (_Float16)a[2]; h[3] = (_Float16)a[3];
  h[4] = (_Float16)b[0]; h[5] = (_Float16)b[1]; h[6] = (_Float16)b[2]; h[7] = (_Float16)b[3];
  *reinterpret_cast<f16x8*>(&dst[(size_t)off * 8]) = h;
}

// -------- merged QKV projection, BM=128 x BN=256 (wave tile 64x128) --------
// X fp32 (inline cvt to f16 in A-staging), W f16 via gl2lds.
// third 0: Q -> f16 [B][S][D], *QSCALE   third 1: K -> f16 [B][S][D]
// third 2: V -> f16 Vt [b][h][dk][s]
__global__ __launch_bounds__(256, 2) void gemm_qkv(
    const float* __restrict__ Xq, const float* __restrict__ Xk, const float* __restrict__ Xv,
    const _Float16* __restrict__ Wq, const _Float16* __restrict__ Wk, const _Float16* __restrict__ Wv,
    const float* __restrict__ bq, const float* __restrict__ bk, const float* __restrict__ bv,
    _Float16* __restrict__ Qh, _Float16* __restrict__ Kh, _Float16* __restrict__ Vt) {
  __shared__ _Float16 As[128 * 72];  // A reg-staged fp32->f16, padded stride 72 (18 KB)
  __shared__ _Float16 Bs[256 * 64];  // B via gl2lds, linear (32 KB)
  const int third = blockIdx.x >> 8;
  const int bid = blockIdx.x & 255;
  const float* X = third == 0 ? Xq : (third == 1 ? Xk : Xv);
  const _Float16* Bw = third == 0 ? Wq : (third == 1 ? Wk : Wv);
  const float* bias = third == 0 ? bq : (third == 1 ? bk : bv);

  const int t = threadIdx.x;
  const int lane = t & 63;
  const int w = t >> 6;
  const int wr = w >> 1, wc = w & 1;       // wave tile: rows wr*64, cols wc*128
  const int l15 = lane & 15, g = lane >> 4;
  const int m0 = (bid & 63) * 128;
  const int n0 = (bid >> 6) * 256;

  f32x4 acc[4][8] = {};
  const int srow = lane >> 3;       // 0..7
  const int schk = (lane & 7) * 8;  // 16B chunk for gl2lds
  const int ar = t >> 4;            // 0..15 (A-stage row within group)
  const int ac = (t & 15) * 4;      // 0..60 (A-stage col)

  for (int kt = 0; kt < 16; ++kt) {
    const int k0 = kt * 64;
    // B: 256 rows x 64 k-cols, 8 wave-groups of 8 rows
#pragma unroll
    for (int u = 0; u < 8; ++u)
      gl2lds(&Bw[(size_t)(n0 + u * 32 + w * 8 + srow) * D_ + k0 + schk], &Bs[u * 2048 + w * 512]);
    // A: 128 rows x 64 k-cols fp32 -> f16, padded stride 72
#pragma unroll
    for (int rg = 0; rg < 8; ++rg) {
      const int r = rg * 16 + ar;
      const f32x4 vv = *reinterpret_cast<const f32x4*>(&X[(size_t)(m0 + r) * D_ + k0 + ac]);
      f16x4 hh;
      hh[0] = (_Float16)vv[0]; hh[1] = (_Float16)vv[1];
      hh[2] = (_Float16)vv[2]; hh[3] = (_Float16)vv[3];
      *reinterpret_cast<f16x4*>(&As[r * 72 + ac]) = hh;
    }
    __syncthreads();
#pragma unroll
    for (int kk = 0; kk < 2; ++kk) {
      f16x8 af[4], bfr[8];
#pragma unroll
      for (int m = 0; m < 4; ++m)
        af[m] = *reinterpret_cast<const f16x8*>(&As[(wr * 64 + m * 16 + l15) * 72 + kk * 32 + 8 * g]);
#pragma unroll
      for (int n = 0; n < 8; ++n)
        bfr[n] = *reinterpret_cast<const f16x8*>(&Bs[(wc * 128 + n * 16 + l15) * 64 + kk * 32 + 8 * g]);
#pragma unroll
      for (int m = 0; m < 4; ++m)
#pragma unroll
        for (int n = 0; n < 8; ++n)
          acc[m][n] = mfma16(af[m], bfr[n], acc[m][n]);
    }
    __syncthreads();
  }

  if (third < 2) {
    _Float16* Y = third == 0 ? Qh : Kh;
    const float scl = third == 0 ? QSCALE : 1.0f;
#pragma unroll
    for (int m = 0; m < 4; ++m)
#pragma unroll
      for (int n = 0; n < 8; ++n)
#pragma unroll
        for (int i = 0; i < 4; ++i) {
          const int R = m0 + wr * 64 + m * 16 + 4 * g + i;
          const int C = n0 + wc * 128 + n * 16 + l15;
          Y[(size_t)R * D_ + C] = (_Float16)((acc[m][n][i] + bias[C]) * scl);
        }
  } else {
#pragma unroll
    for (int m = 0; m < 4; ++m)
#pragma unroll
      for (int n = 0; n < 8; ++n) {
        const int R0 = m0 + wr * 64 + m * 16 + 4 * g;
        const int C = n0 + wc * 128 + n * 16 + l15;
        const int b = R0 >> 11, s0 = R0 & (S_ - 1);
        const int h = C >> 6, dk = C & (DK_ - 1);
        f16x4 hv;
#pragma unroll
        for (int i = 0; i < 4; ++i) hv[i] = (_Float16)(acc[m][n][i] + bias[C]);
        *reinterpret_cast<f16x4*>(&Vt[((size_t)((b * H_ + h) * DK_ + dk)) * S_ + s0]) = hv;
      }
  }
}

// ---------------- out GEMM, BM=128 x BN=256: out = ctx @ Wo^T + b (fp32) ----------------
__global__ __launch_bounds__(256, 2) void gemm_out(const _Float16* __restrict__ A,
                                                   const _Float16* __restrict__ Bw,
                                                   const float* __restrict__ bias,
                                                   float* __restrict__ out) {
  __shared__ _Float16 As[128 * 64];
  __shared__ _Float16 Bs[256 * 64];
  const int t = threadIdx.x;
  const int lane = t & 63;
  const int w = t >> 6;
  const int wr = w >> 1, wc = w & 1;
  const int l15 = lane & 15, g = lane >> 4;
  const int m0 = (blockIdx.x & 63) * 128;
  const int n0 = (blockIdx.x >> 6) * 256;

  f32x4 acc[4][8] = {};
  const int srow = lane >> 3;
  const int schk = (lane & 7) * 8;

  for (int kt = 0; kt < 16; ++kt) {
    const int k0 = kt * 64;
#pragma unroll
    for (int u = 0; u < 4; ++u)
      gl2lds(&A[(size_t)(m0 + u * 32 + w * 8 + srow) * D_ + k0 + schk], &As[u * 2048 + w * 512]);
#pragma unroll
    for (int u = 0; u < 8; ++u)
      gl2lds(&Bw[(size_t)(n0 + u * 32 + w * 8 + srow) * D_ + k0 + schk], &Bs[u * 2048 + w * 512]);
    __syncthreads();
#pragma unroll
    for (int kk = 0; kk < 2; ++kk) {
      f16x8 af[4], bfr[8];
#pragma unroll
      for (int m = 0; m < 4; ++m)
        af[m] = *reinterpret_cast<const f16x8*>(&As[(wr * 64 + m * 16 + l15) * 64 + kk * 32 + 8 * g]);
#pragma unroll
      for (int n = 0; n < 8; ++n)
        bfr[n] = *reinterpret_cast<const f16x8*>(&Bs[(wc * 128 + n * 16 + l15) * 64 + kk * 32 + 8 * g]);
#pragma unroll
      for (int m = 0; m < 4; ++m)
#pragma unroll
        for (int n = 0; n < 8; ++n)
          acc[m][n] = mfma16(af[m], bfr[n], acc[m][n]);
    }
    __syncthreads();
  }

#pragma unroll
  for (int m = 0; m < 4; ++m)
#pragma unroll
    for (int n = 0; n < 8; ++n)
#pragma unroll
      for (int i = 0; i < 4; ++i) {
        const int R = m0 + wr * 64 + m * 16 + 4 * g + i;
        const int C = n0 + wc * 128 + n * 16 + l15;
        out[(size_t)R * D_ + C] = acc[m][n][i] + bias[C];
      }
}

// ------- fused attention: phase A = pass1-style row sums (waves split columns over the
// block's 128 rows, 16 MFMA : 2 loads), one barrier; phase B = R7 pass2 unchanged -------
__global__ __launch_bounds__(256) void attn_fused(const _Float16* __restrict__ Qh,
                                                  const _Float16* __restrict__ Kh,
                                                  const _Float16* __restrict__ Vt,
                                                  float* __restrict__ attn,
                                                  _Float16* __restrict__ ctx) {
  __shared__ float Ps[4][32 * 36];  // per-wave 32x32 fp32 P tile, stride 36
  __shared__ float red[4][128];     // per-wave partial row sums
  const int t = threadIdx.x;
  const int lane = t & 63;
  const int w = t >> 6;
  const int l15 = lane & 15, g = lane >> 4;
  const int qc = blockIdx.x & 15;  // S_/128
  const int bh = blockIdx.x >> 4;
  const int b = bh >> 4, h = bh & 15;
  const int q0b = qc * 128;        // block row base
  const int q0 = q0b + w * 32;     // this wave's phase-B rows
  const _Float16* Qp = Qh + (size_t)b * S_ * D_ + h * DK_;
  const _Float16* Kp = Kh + (size_t)b * S_ * D_ + h * DK_;
  const _Float16* Vp = Vt + (size_t)bh * DK_ * S_;

  // ---- phase A: row sums of exp2(scores) for ALL 128 block rows over this wave's 512 cols ----
  {
    f16x8 qaA[8][2];
#pragma unroll
    for (int mr = 0; mr < 8; ++mr)
#pragma unroll
      for (int kk = 0; kk < 2; ++kk)
        qaA[mr][kk] = *reinterpret_cast<const f16x8*>(&Qp[(size_t)(q0b + mr * 16 + l15) * D_ + kk * 32 + 8 * g]);

    float l[8][4] = {};
    const int cbeg = w * (S_ / 4), cend = cbeg + (S_ / 4);
    f16x8 kb0 = *reinterpret_cast<const f16x8*>(&Kp[(size_t)(cbeg + l15) * D_ + 8 * g]);
    f16x8 kb1 = *reinterpret_cast<const f16x8*>(&Kp[(size_t)(cbeg + l15) * D_ + 32 + 8 * g]);
    for (int c0 = cbeg; c0 < cend; c0 += 16) {
      const int cn = (c0 + 16 < cend) ? c0 + 16 : cbeg;  // prefetch next (wrap harmless)
      const f16x8 nb0 = *reinterpret_cast<const f16x8*>(&Kp[(size_t)(cn + l15) * D_ + 8 * g]);
      const f16x8 nb1 = *reinterpret_cast<const f16x8*>(&Kp[(size_t)(cn + l15) * D_ + 32 + 8 * g]);
#pragma unroll
      for (int mr = 0; mr < 8; ++mr) {
        f32x4 sc = {};
        sc = mfma16(qaA[mr][0], kb0, sc);
        sc = mfma16(qaA[mr][1], kb1, sc);
#pragma unroll
        for (int i = 0; i < 4; ++i) l[mr][i] += exp2f(sc[i]);
      }
      kb0 = nb0; kb1 = nb1;
    }
#pragma unroll
    for (int mask = 1; mask < 16; mask <<= 1)
#pragma unroll
      for (int mr = 0; mr < 8; ++mr)
#pragma unroll
        for (int i = 0; i < 4; ++i) l[mr][i] += __shfl_xor(l[mr][i], mask, 64);
    if (l15 == 0)
#pragma unroll
      for (int mr = 0; mr < 8; ++mr)
#pragma unroll
        for (int i = 0; i < 4; ++i) red[w][mr * 16 + 4 * g + i] = l[mr][i];
  }
  __syncthreads();

  float il[2][4];
#pragma unroll
  for (int mr = 0; mr < 2; ++mr)
#pragma unroll
    for (int i = 0; i < 4; ++i) {
      const int rl = w * 32 + mr * 16 + 4 * g + i;
      il[mr][i] = 1.0f / (red[0][rl] + red[1][rl] + red[2][rl] + red[3][rl]);
    }

  // ---- phase B: recompute scores, write normalized P, ctx = P @ V (R7 structure) ----
  f16x8 qa[2][2];
#pragma unroll
  for (int mr = 0; mr < 2; ++mr)
#pragma unroll
    for (int kk = 0; kk < 2; ++kk)
      qa[mr][kk] = *reinterpret_cast<const f16x8*>(&Qp[(size_t)(q0 + mr * 16 + l15) * D_ + kk * 32 + 8 * g]);

  f32x4 accv[2][4] = {};
  float* Pw = Ps[w];
  const int sr = lane >> 3;        // 0..7  (store row group)
  const int sc4 = (lane & 7) * 4;  // 0..28 (store col chunk)

#pragma unroll 2
  for (int c0 = 0; c0 < S_; c0 += 32) {
#pragma unroll
    for (int ct = 0; ct < 2; ++ct) {
      const f16x8 kb0 = *reinterpret_cast<const f16x8*>(&Kp[(size_t)(c0 + ct * 16 + l15) * D_ + 8 * g]);
      const f16x8 kb1 = *reinterpret_cast<const f16x8*>(&Kp[(size_t)(c0 + ct * 16 + l15) * D_ + 32 + 8 * g]);
#pragma unroll
      for (int mr = 0; mr < 2; ++mr) {
        f32x4 sc = {};
        sc = mfma16(qa[mr][0], kb0, sc);
        sc = mfma16(qa[mr][1], kb1, sc);
#pragma unroll
        for (int i = 0; i < 4; ++i)
          Pw[(mr * 16 + 4 * g + i) * 36 + ct * 16 + l15] = exp2f(sc[i]) * il[mr][i];
      }
    }
    // attn store: 32 rows x 32 cols, 128B-contiguous per row (plain stores via L2)
#pragma unroll
    for (int j = 0; j < 4; ++j) {
      const int r = sr + 8 * j;
      const f32x4 pv = *reinterpret_cast<const f32x4*>(&Pw[r * 36 + sc4]);
      *reinterpret_cast<f32x4*>(&attn[((size_t)bh * S_ + q0 + r) * S_ + c0 + sc4]) = pv;
    }
    // PV: re-fragment P from LDS (fp32 -> f16), B from Vt (contiguous along s)
#pragma unroll
    for (int mr = 0; mr < 2; ++mr) {
      const f32x4 p0 = *reinterpret_cast<const f32x4*>(&Pw[(mr * 16 + l15) * 36 + 8 * g]);
      const f32x4 p1 = *reinterpret_cast<const f32x4*>(&Pw[(mr * 16 + l15) * 36 + 8 * g + 4]);
      f16x8 pa;
#pragma unroll
      for (int j = 0; j < 4; ++j) { pa[j] = (_Float16)p0[j]; pa[4 + j] = (_Float16)p1[j]; }
#pragma unroll
      for (int n = 0; n < 4; ++n) {
        const f16x8 vb = *reinterpret_cast<const f16x8*>(&Vp[(size_t)(n * 16 + l15) * S_ + c0 + 8 * g]);
        accv[mr][n] = mfma16(pa, vb, accv[mr][n]);
      }
    }
  }
#pragma unroll
  for (int mr = 0; mr < 2; ++mr)
#pragma unroll
    for (int n = 0; n < 4; ++n)
#pragma unroll
      for (int i = 0; i < 4; ++i) {
        const int row = q0 + mr * 16 + 4 * g + i;
        ctx[((size_t)(b * S_ + row)) * D_ + h * DK_ + n * 16 + l15] = (_Float16)accv[mr][n][i];
      }
}

// ---------------- residual + LayerNorm: one row per wave, no LDS ----------------
__global__ __launch_bounds__(256) void ln_kernel(float* __restrict__ out,
                                                 const float* __restrict__ resid,
                                                 const float* __restrict__ gamma,
                                                 const float* __restrict__ beta) {
  const int t = threadIdx.x;
  const int lane = t & 63, w = t >> 6;
  const int row = blockIdx.x * 4 + w;
  const size_t rb = (size_t)row * D_;
  f32x4 x[4];
  float s = 0.f, s2 = 0.f;
#pragma unroll
  for (int c = 0; c < 4; ++c) {
    const int off = c * 256 + lane * 4;
    const f32x4 o = *reinterpret_cast<const f32x4*>(&out[rb + off]);
    const f32x4 r = *reinterpret_cast<const f32x4*>(&resid[rb + off]);
    x[c] = o + r;
#pragma unroll
    for (int j = 0; j < 4; ++j) { s += x[c][j]; s2 += x[c][j] * x[c][j]; }
  }
#pragma unroll
  for (int mask = 1; mask < 64; mask <<= 1) {
    s += __shfl_xor(s, mask, 64);
    s2 += __shfl_xor(s2, mask, 64);
  }
  const float mu = s * (1.0f / D_);
  const float var = s2 * (1.0f / D_) - mu * mu;
  const float rstd = rsqrtf(var + 1e-5f);
#pragma unroll
  for (int c = 0; c < 4; ++c) {
    const int off = c * 256 + lane * 4;
    const f32x4 gm = *reinterpret_cast<const f32x4*>(&gamma[off]);
    const f32x4 bt = *reinterpret_cast<const f32x4*>(&beta[off]);
    f32x4 y;
#pragma unroll
    for (int j = 0; j < 4; ++j) y[j] = (x[c][j] - mu) * rstd * gm[j] + bt[j];
    *reinterpret_cast<f32x4*>(&out[rb + off]) = y;
  }
}

extern "C" void kernel_launch(void* const* d_in, const int* in_sizes, int n_in,
                              void* d_out, int out_size, void* d_ws, size_t ws_size,
                              hipStream_t stream) {
  (void)in_sizes; (void)n_in; (void)out_size; (void)ws_size;
  const float* q    = (const float*)d_in[0];
  const float* k    = (const float*)d_in[1];
  const float* v    = (const float*)d_in[2];
  const float* w_q  = (const float*)d_in[3];
  const float* b_q  = (const float*)d_in[4];
  const float* w_k  = (const float*)d_in[5];
  const float* b_k  = (const float*)d_in[6];
  const float* w_v  = (const float*)d_in[7];
  const float* b_v  = (const float*)d_in[8];
  const float* w_o  = (const float*)d_in[9];
  const float* b_o  = (const float*)d_in[10];
  const float* ln_g = (const float*)d_in[11];
  const float* ln_b = (const float*)d_in[12];

  char* ws = (char*)d_ws;
  _Float16* wq_h = (_Float16*)(ws + ((size_t)0 << 20));
  _Float16* wk_h = (_Float16*)(ws + ((size_t)2 << 20));
  _Float16* wv_h = (_Float16*)(ws + ((size_t)4 << 20));
  _Float16* wo_h = (_Float16*)(ws + ((size_t)6 << 20));
  _Float16* Qh   = (_Float16*)(ws + ((size_t)8 << 20));   // [B][S][D], pre-scaled QSCALE
  _Float16* Kh   = (_Float16*)(ws + ((size_t)26 << 20));  // [B][S][D]
  _Float16* Vt   = (_Float16*)(ws + ((size_t)44 << 20));  // [B][H][DK][S]
  _Float16* ctx  = (_Float16*)(ws + ((size_t)62 << 20));  // [M][1024]

  float* out_f = (float*)d_out;
  float* attn_f = out_f + (size_t)M_ * D_;

  cvt_w<<<4 * NW8 / 256, 256, 0, stream>>>(w_q, w_k, w_v, w_o, wq_h, wk_h, wv_h, wo_h);

  gemm_qkv<<<768, 256, 0, stream>>>(q, k, v, wq_h, wk_h, wv_h, b_q, b_k, b_v, Qh, Kh, Vt);

  attn_fused<<<B_ * H_ * (S_ / 128), 256, 0, stream>>>(Qh, Kh, Vt, attn_f, ctx);

  gemm_out<<<256, 256, 0, stream>>>(ctx, wo_h, b_o, out_f);
  ln_kernel<<<M_ / 4, 256, 0, stream>>>(out_f, q, ln_g, ln_b);
}

// Round 10
// 497.377 us; speedup vs baseline: 1.3616x; 1.3616x over previous
//
#include <hip/hip_runtime.h>

// MultiHeadAttention: B=4 S=2048 D=1024 H=16 DK=64
// outputs: [out (B,S,D) fp32 ; attn (B,H,S,S) fp32]
#define B_ 4
#define S_ 2048
#define D_ 1024
#define H_ 16
#define DK_ 64
#define M_ (B_ * S_) /* 8192 */

typedef __attribute__((ext_vector_type(8))) _Float16 f16x8;
typedef __attribute__((ext_vector_type(4))) _Float16 f16x4;
typedef __attribute__((ext_vector_type(4))) float f32x4;

#define QSCALE 0.18033688011113607f /* 0.125 * log2(e) */

__device__ __forceinline__ f32x4 mfma16(f16x8 a, f16x8 b, f32x4 c) {
  return __builtin_amdgcn_mfma_f32_16x16x32_f16(a, b, c, 0, 0, 0);
}

// async global->LDS, 16B per lane; LDS dest is wave-uniform base + lane*16
__device__ __forceinline__ void gl2lds(const _Float16* g, _Float16* l) {
  __builtin_amdgcn_global_load_lds(
      (const __attribute__((address_space(1))) void*)g,
      (__attribute__((address_space(3))) void*)l, 16, 0, 0);
}

// ---------------- fp32 -> f16 for the 4 weight matrices ----------------
#define NW8 (D_ * D_ / 8) /* 131072 = 1<<17 */
__global__ __launch_bounds__(256) void cvt_w(
    const float* __restrict__ wq, const float* __restrict__ wk,
    const float* __restrict__ wv, const float* __restrict__ wo,
    _Float16* __restrict__ wqh, _Float16* __restrict__ wkh,
    _Float16* __restrict__ wvh, _Float16* __restrict__ woh) {
  const int i = blockIdx.x * 256 + threadIdx.x;
  const int t = i >> 17;
  const int off = i & (NW8 - 1);
  const float* src = t == 0 ? wq : (t == 1 ? wk : (t == 2 ? wv : wo));
  _Float16* dst = t == 0 ? wqh : (t == 1 ? wkh : (t == 2 ? wvh : woh));
  const f32x4 a = *reinterpret_cast<const f32x4*>(&src[(size_t)off * 8]);
  const f32x4 b = *reinterpret_cast<const f32x4*>(&src[(size_t)off * 8 + 4]);
  f16x8 h;
  h[0] = (_Float16)a[0]; h[1] = (_Float16)a[1]; h[2] = (_Float16)a[2]; h[3] = (_Float16)a[3];
  h[4] = (_Float16)b[0]; h[5] = (_Float16)b[1]; h[6] = (_Float16)b[2]; h[7] = (_Float16)b[3];
  *reinterpret_cast<f16x8*>(&dst[(size_t)off * 8]) = h;
}

// -------- merged QKV projection, BM=128 x BN=256 (wave tile 64x128) --------
// X fp32 (inline cvt to f16 in A-staging), W f16 via gl2lds.
// third 0: Q -> f16 [B][S][D], *QSCALE   third 1: K -> f16 [B][S][D]
// third 2: V -> f16 Vt [b][h][dk][s]
__global__ __launch_bounds__(256, 2) void gemm_qkv(
    const float* __restrict__ Xq, const float* __restrict__ Xk, const float* __restrict__ Xv,
    const _Float16* __restrict__ Wq, const _Float16* __restrict__ Wk, const _Float16* __restrict__ Wv,
    const float* __restrict__ bq, const float* __restrict__ bk, const float* __restrict__ bv,
    _Float16* __restrict__ Qh, _Float16* __restrict__ Kh, _Float16* __restrict__ Vt) {
  __shared__ _Float16 As[128 * 72];  // A reg-staged fp32->f16, padded stride 72 (18 KB)
  __shared__ _Float16 Bs[256 * 64];  // B via gl2lds, linear (32 KB)
  const int third = blockIdx.x >> 8;
  const int bid = blockIdx.x & 255;
  const float* X = third == 0 ? Xq : (third == 1 ? Xk : Xv);
  const _Float16* Bw = third == 0 ? Wq : (third == 1 ? Wk : Wv);
  const float* bias = third == 0 ? bq : (third == 1 ? bk : bv);

  const int t = threadIdx.x;
  const int lane = t & 63;
  const int w = t >> 6;
  const int wr = w >> 1, wc = w & 1;       // wave tile: rows wr*64, cols wc*128
  const int l15 = lane & 15, g = lane >> 4;
  const int m0 = (bid & 63) * 128;
  const int n0 = (bid >> 6) * 256;

  f32x4 acc[4][8] = {};
  const int srow = lane >> 3;       // 0..7
  const int schk = (lane & 7) * 8;  // 16B chunk for gl2lds
  const int ar = t >> 4;            // 0..15 (A-stage row within group)
  const int ac = (t & 15) * 4;      // 0..60 (A-stage col)

  for (int kt = 0; kt < 16; ++kt) {
    const int k0 = kt * 64;
    // B: 256 rows x 64 k-cols, 8 wave-groups of 8 rows
#pragma unroll
    for (int u = 0; u < 8; ++u)
      gl2lds(&Bw[(size_t)(n0 + u * 32 + w * 8 + srow) * D_ + k0 + schk], &Bs[u * 2048 + w * 512]);
    // A: 128 rows x 64 k-cols fp32 -> f16, padded stride 72
#pragma unroll
    for (int rg = 0; rg < 8; ++rg) {
      const int r = rg * 16 + ar;
      const f32x4 vv = *reinterpret_cast<const f32x4*>(&X[(size_t)(m0 + r) * D_ + k0 + ac]);
      f16x4 hh;
      hh[0] = (_Float16)vv[0]; hh[1] = (_Float16)vv[1];
      hh[2] = (_Float16)vv[2]; hh[3] = (_Float16)vv[3];
      *reinterpret_cast<f16x4*>(&As[r * 72 + ac]) = hh;
    }
    __syncthreads();
#pragma unroll
    for (int kk = 0; kk < 2; ++kk) {
      f16x8 af[4], bfr[8];
#pragma unroll
      for (int m = 0; m < 4; ++m)
        af[m] = *reinterpret_cast<const f16x8*>(&As[(wr * 64 + m * 16 + l15) * 72 + kk * 32 + 8 * g]);
#pragma unroll
      for (int n = 0; n < 8; ++n)
        bfr[n] = *reinterpret_cast<const f16x8*>(&Bs[(wc * 128 + n * 16 + l15) * 64 + kk * 32 + 8 * g]);
#pragma unroll
      for (int m = 0; m < 4; ++m)
#pragma unroll
        for (int n = 0; n < 8; ++n)
          acc[m][n] = mfma16(af[m], bfr[n], acc[m][n]);
    }
    __syncthreads();
  }

  if (third < 2) {
    _Float16* Y = third == 0 ? Qh : Kh;
    const float scl = third == 0 ? QSCALE : 1.0f;
#pragma unroll
    for (int m = 0; m < 4; ++m)
#pragma unroll
      for (int n = 0; n < 8; ++n)
#pragma unroll
        for (int i = 0; i < 4; ++i) {
          const int R = m0 + wr * 64 + m * 16 + 4 * g + i;
          const int C = n0 + wc * 128 + n * 16 + l15;
          Y[(size_t)R * D_ + C] = (_Float16)((acc[m][n][i] + bias[C]) * scl);
        }
  } else {
#pragma unroll
    for (int m = 0; m < 4; ++m)
#pragma unroll
      for (int n = 0; n < 8; ++n) {
        const int R0 = m0 + wr * 64 + m * 16 + 4 * g;
        const int C = n0 + wc * 128 + n * 16 + l15;
        const int b = R0 >> 11, s0 = R0 & (S_ - 1);
        const int h = C >> 6, dk = C & (DK_ - 1);
        f16x4 hv;
#pragma unroll
        for (int i = 0; i < 4; ++i) hv[i] = (_Float16)(acc[m][n][i] + bias[C]);
        *reinterpret_cast<f16x4*>(&Vt[((size_t)((b * H_ + h) * DK_ + dk)) * S_ + s0]) = hv;
      }
  }
}

// ---------------- out GEMM, BM=128 x BN=256: out = ctx @ Wo^T + b (fp32) ----------------
__global__ __launch_bounds__(256, 2) void gemm_out(const _Float16* __restrict__ A,
                                                   const _Float16* __restrict__ Bw,
                                                   const float* __restrict__ bias,
                                                   float* __restrict__ out) {
  __shared__ _Float16 As[128 * 64];
  __shared__ _Float16 Bs[256 * 64];
  const int t = threadIdx.x;
  const int lane = t & 63;
  const int w = t >> 6;
  const int wr = w >> 1, wc = w & 1;
  const int l15 = lane & 15, g = lane >> 4;
  const int m0 = (blockIdx.x & 63) * 128;
  const int n0 = (blockIdx.x >> 6) * 256;

  f32x4 acc[4][8] = {};
  const int srow = lane >> 3;
  const int schk = (lane & 7) * 8;

  for (int kt = 0; kt < 16; ++kt) {
    const int k0 = kt * 64;
#pragma unroll
    for (int u = 0; u < 4; ++u)
      gl2lds(&A[(size_t)(m0 + u * 32 + w * 8 + srow) * D_ + k0 + schk], &As[u * 2048 + w * 512]);
#pragma unroll
    for (int u = 0; u < 8; ++u)
      gl2lds(&Bw[(size_t)(n0 + u * 32 + w * 8 + srow) * D_ + k0 + schk], &Bs[u * 2048 + w * 512]);
    __syncthreads();
#pragma unroll
    for (int kk = 0; kk < 2; ++kk) {
      f16x8 af[4], bfr[8];
#pragma unroll
      for (int m = 0; m < 4; ++m)
        af[m] = *reinterpret_cast<const f16x8*>(&As[(wr * 64 + m * 16 + l15) * 64 + kk * 32 + 8 * g]);
#pragma unroll
      for (int n = 0; n < 8; ++n)
        bfr[n] = *reinterpret_cast<const f16x8*>(&Bs[(wc * 128 + n * 16 + l15) * 64 + kk * 32 + 8 * g]);
#pragma unroll
      for (int m = 0; m < 4; ++m)
#pragma unroll
        for (int n = 0; n < 8; ++n)
          acc[m][n] = mfma16(af[m], bfr[n], acc[m][n]);
    }
    __syncthreads();
  }

#pragma unroll
  for (int m = 0; m < 4; ++m)
#pragma unroll
    for (int n = 0; n < 8; ++n)
#pragma unroll
      for (int i = 0; i < 4; ++i) {
        const int R = m0 + wr * 64 + m * 16 + 4 * g + i;
        const int C = n0 + wc * 128 + n * 16 + l15;
        out[(size_t)R * D_ + C] = acc[m][n][i] + bias[C];
      }
}

// ---------------- attention pass 1: row sums of exp2(scores) ----------------
// Qh pre-scaled by 0.125*log2(e); scores bounded -> exp2 safe without max-subtraction.
// Waves split the column range (K read once per block); K-frags prefetched one step ahead.
__global__ __launch_bounds__(256) void attn_pass1(const _Float16* __restrict__ Qh,
                                                  const _Float16* __restrict__ Kh,
                                                  float* __restrict__ lbuf) {
  __shared__ float red[4][64];
  const int t = threadIdx.x;
  const int lane = t & 63;
  const int w = t >> 6;
  const int l15 = lane & 15, g = lane >> 4;
  const int qc = blockIdx.x & 31;  // S_/64
  const int bh = blockIdx.x >> 5;
  const int b = bh >> 4, h = bh & 15;
  const int q0 = qc * 64;
  const _Float16* Qp = Qh + (size_t)b * S_ * D_ + h * DK_;
  const _Float16* Kp = Kh + (size_t)b * S_ * D_ + h * DK_;

  f16x8 qa[4][2];
#pragma unroll
  for (int mr = 0; mr < 4; ++mr)
#pragma unroll
    for (int kk = 0; kk < 2; ++kk)
      qa[mr][kk] = *reinterpret_cast<const f16x8*>(&Qp[(size_t)(q0 + mr * 16 + l15) * D_ + kk * 32 + 8 * g]);

  float l[4][4] = {};
  const int cbeg = w * (S_ / 4), cend = cbeg + (S_ / 4);
  f16x8 kb0 = *reinterpret_cast<const f16x8*>(&Kp[(size_t)(cbeg + l15) * D_ + 8 * g]);
  f16x8 kb1 = *reinterpret_cast<const f16x8*>(&Kp[(size_t)(cbeg + l15) * D_ + 32 + 8 * g]);
  for (int c0 = cbeg; c0 < cend; c0 += 16) {
    const int cn = (c0 + 16 < cend) ? c0 + 16 : cbeg;  // prefetch next (wrap harmless)
    const f16x8 nb0 = *reinterpret_cast<const f16x8*>(&Kp[(size_t)(cn + l15) * D_ + 8 * g]);
    const f16x8 nb1 = *reinterpret_cast<const f16x8*>(&Kp[(size_t)(cn + l15) * D_ + 32 + 8 * g]);
#pragma unroll
    for (int mr = 0; mr < 4; ++mr) {
      f32x4 sc = {};
      sc = mfma16(qa[mr][0], kb0, sc);
      sc = mfma16(qa[mr][1], kb1, sc);
#pragma unroll
      for (int i = 0; i < 4; ++i) l[mr][i] += exp2f(sc[i]);
    }
    kb0 = nb0; kb1 = nb1;
  }
#pragma unroll
  for (int mask = 1; mask < 16; mask <<= 1)
#pragma unroll
    for (int mr = 0; mr < 4; ++mr)
#pragma unroll
      for (int i = 0; i < 4; ++i) l[mr][i] += __shfl_xor(l[mr][i], mask, 64);
  if (l15 == 0)
#pragma unroll
    for (int mr = 0; mr < 4; ++mr)
#pragma unroll
      for (int i = 0; i < 4; ++i) red[w][mr * 16 + 4 * g + i] = l[mr][i];
  __syncthreads();
  if (t < 64)
    lbuf[(size_t)bh * S_ + q0 + t] = red[0][t] + red[1][t] + red[2][t] + red[3][t];
}

// ------- pass 2: recompute scores, write normalized P (vectorized NT), ctx = P @ V -------
__global__ __launch_bounds__(256) void attn_pass2(const _Float16* __restrict__ Qh,
                                                  const _Float16* __restrict__ Kh,
                                                  const _Float16* __restrict__ Vt,
                                                  const float* __restrict__ lbuf,
                                                  float* __restrict__ attn,
                                                  _Float16* __restrict__ ctx) {
  __shared__ float Ps[4][32 * 36];  // per-wave 32x32 fp32 P tile, stride 36 (16B-aligned rows)
  const int t = threadIdx.x;
  const int lane = t & 63;
  const int w = t >> 6;
  const int l15 = lane & 15, g = lane >> 4;
  const int qc = blockIdx.x & 15;  // S_/128
  const int bh = blockIdx.x >> 4;
  const int b = bh >> 4, h = bh & 15;
  const int q0 = qc * 128 + w * 32;
  const _Float16* Qp = Qh + (size_t)b * S_ * D_ + h * DK_;
  const _Float16* Kp = Kh + (size_t)b * S_ * D_ + h * DK_;
  const _Float16* Vp = Vt + (size_t)bh * DK_ * S_;

  f16x8 qa[2][2];
#pragma unroll
  for (int mr = 0; mr < 2; ++mr)
#pragma unroll
    for (int kk = 0; kk < 2; ++kk)
      qa[mr][kk] = *reinterpret_cast<const f16x8*>(&Qp[(size_t)(q0 + mr * 16 + l15) * D_ + kk * 32 + 8 * g]);

  float il[2][4];
#pragma unroll
  for (int mr = 0; mr < 2; ++mr)
#pragma unroll
    for (int i = 0; i < 4; ++i)
      il[mr][i] = 1.0f / lbuf[(size_t)bh * S_ + q0 + mr * 16 + 4 * g + i];

  f32x4 accv[2][4] = {};
  float* Pw = Ps[w];
  const int sr = lane >> 3;        // 0..7  (store row group)
  const int sc4 = (lane & 7) * 4;  // 0..28 (store col chunk)

  // No barrier in this loop (per-wave LDS tile) -> unroll 2 lets the scheduler
  // overlap one tile's NT stores / LDS ops with the next tile's MFMA+exp.
#pragma unroll 2
  for (int c0 = 0; c0 < S_; c0 += 32) {
#pragma unroll
    for (int ct = 0; ct < 2; ++ct) {
      const f16x8 kb0 = *reinterpret_cast<const f16x8*>(&Kp[(size_t)(c0 + ct * 16 + l15) * D_ + 8 * g]);
      const f16x8 kb1 = *reinterpret_cast<const f16x8*>(&Kp[(size_t)(c0 + ct * 16 + l15) * D_ + 32 + 8 * g]);
#pragma unroll
      for (int mr = 0; mr < 2; ++mr) {
        f32x4 sc = {};
        sc = mfma16(qa[mr][0], kb0, sc);
        sc = mfma16(qa[mr][1], kb1, sc);
#pragma unroll
        for (int i = 0; i < 4; ++i)
          Pw[(mr * 16 + 4 * g + i) * 36 + ct * 16 + l15] = exp2f(sc[i]) * il[mr][i];
      }
    }
    // vectorized attn store: 32 rows x 32 cols, 128B-contiguous per row
#pragma unroll
    for (int j = 0; j < 4; ++j) {
      const int r = sr + 8 * j;
      const f32x4 pv = *reinterpret_cast<const f32x4*>(&Pw[r * 36 + sc4]);
      __builtin_nontemporal_store(pv,
          reinterpret_cast<f32x4*>(&attn[((size_t)bh * S_ + q0 + r) * S_ + c0 + sc4]));
    }
    // PV: re-fragment P from LDS (fp32 -> f16), B from Vt (contiguous along s)
#pragma unroll
    for (int mr = 0; mr < 2; ++mr) {
      const f32x4 p0 = *reinterpret_cast<const f32x4*>(&Pw[(mr * 16 + l15) * 36 + 8 * g]);
      const f32x4 p1 = *reinterpret_cast<const f32x4*>(&Pw[(mr * 16 + l15) * 36 + 8 * g + 4]);
      f16x8 pa;
#pragma unroll
      for (int j = 0; j < 4; ++j) { pa[j] = (_Float16)p0[j]; pa[4 + j] = (_Float16)p1[j]; }
#pragma unroll
      for (int n = 0; n < 4; ++n) {
        const f16x8 vb = *reinterpret_cast<const f16x8*>(&Vp[(size_t)(n * 16 + l15) * S_ + c0 + 8 * g]);
        accv[mr][n] = mfma16(pa, vb, accv[mr][n]);
      }
    }
  }
#pragma unroll
  for (int mr = 0; mr < 2; ++mr)
#pragma unroll
    for (int n = 0; n < 4; ++n)
#pragma unroll
      for (int i = 0; i < 4; ++i) {
        const int row = q0 + mr * 16 + 4 * g + i;
        ctx[((size_t)(b * S_ + row)) * D_ + h * DK_ + n * 16 + l15] = (_Float16)accv[mr][n][i];
      }
}

// ---------------- residual + LayerNorm: one row per wave, no LDS ----------------
__global__ __launch_bounds__(256) void ln_kernel(float* __restrict__ out,
                                                 const float* __restrict__ resid,
                                                 const float* __restrict__ gamma,
                                                 const float* __restrict__ beta) {
  const int t = threadIdx.x;
  const int lane = t & 63, w = t >> 6;
  const int row = blockIdx.x * 4 + w;
  const size_t rb = (size_t)row * D_;
  f32x4 x[4];
  float s = 0.f, s2 = 0.f;
#pragma unroll
  for (int c = 0; c < 4; ++c) {
    const int off = c * 256 + lane * 4;
    const f32x4 o = *reinterpret_cast<const f32x4*>(&out[rb + off]);
    const f32x4 r = *reinterpret_cast<const f32x4*>(&resid[rb + off]);
    x[c] = o + r;
#pragma unroll
    for (int j = 0; j < 4; ++j) { s += x[c][j]; s2 += x[c][j] * x[c][j]; }
  }
#pragma unroll
  for (int mask = 1; mask < 64; mask <<= 1) {
    s += __shfl_xor(s, mask, 64);
    s2 += __shfl_xor(s2, mask, 64);
  }
  const float mu = s * (1.0f / D_);
  const float var = s2 * (1.0f / D_) - mu * mu;
  const float rstd = rsqrtf(var + 1e-5f);
#pragma unroll
  for (int c = 0; c < 4; ++c) {
    const int off = c * 256 + lane * 4;
    const f32x4 gm = *reinterpret_cast<const f32x4*>(&gamma[off]);
    const f32x4 bt = *reinterpret_cast<const f32x4*>(&beta[off]);
    f32x4 y;
#pragma unroll
    for (int j = 0; j < 4; ++j) y[j] = (x[c][j] - mu) * rstd * gm[j] + bt[j];
    *reinterpret_cast<f32x4*>(&out[rb + off]) = y;
  }
}

extern "C" void kernel_launch(void* const* d_in, const int* in_sizes, int n_in,
                              void* d_out, int out_size, void* d_ws, size_t ws_size,
                              hipStream_t stream) {
  (void)in_sizes; (void)n_in; (void)out_size; (void)ws_size;
  const float* q    = (const float*)d_in[0];
  const float* k    = (const float*)d_in[1];
  const float* v    = (const float*)d_in[2];
  const float* w_q  = (const float*)d_in[3];
  const float* b_q  = (const float*)d_in[4];
  const float* w_k  = (const float*)d_in[5];
  const float* b_k  = (const float*)d_in[6];
  const float* w_v  = (const float*)d_in[7];
  const float* b_v  = (const float*)d_in[8];
  const float* w_o  = (const float*)d_in[9];
  const float* b_o  = (const float*)d_in[10];
  const float* ln_g = (const float*)d_in[11];
  const float* ln_b = (const float*)d_in[12];

  char* ws = (char*)d_ws;
  _Float16* wq_h = (_Float16*)(ws + ((size_t)0 << 20));
  _Float16* wk_h = (_Float16*)(ws + ((size_t)2 << 20));
  _Float16* wv_h = (_Float16*)(ws + ((size_t)4 << 20));
  _Float16* wo_h = (_Float16*)(ws + ((size_t)6 << 20));
  _Float16* Qh   = (_Float16*)(ws + ((size_t)8 << 20));   // [B][S][D], pre-scaled QSCALE
  _Float16* Kh   = (_Float16*)(ws + ((size_t)26 << 20));  // [B][S][D]
  _Float16* Vt   = (_Float16*)(ws + ((size_t)44 << 20));  // [B][H][DK][S]
  _Float16* ctx  = (_Float16*)(ws + ((size_t)62 << 20));  // [M][1024]
  float*    lbuf = (float*)(ws + ((size_t)80 << 20));     // [64][2048]

  float* out_f = (float*)d_out;
  float* attn_f = out_f + (size_t)M_ * D_;

  cvt_w<<<4 * NW8 / 256, 256, 0, stream>>>(w_q, w_k, w_v, w_o, wq_h, wk_h, wv_h, wo_h);

  gemm_qkv<<<768, 256, 0, stream>>>(q, k, v, wq_h, wk_h, wv_h, b_q, b_k, b_v, Qh, Kh, Vt);

  attn_pass1<<<B_ * H_ * (S_ / 64), 256, 0, stream>>>(Qh, Kh, lbuf);
  attn_pass2<<<B_ * H_ * (S_ / 128), 256, 0, stream>>>(Qh, Kh, Vt, lbuf, attn_f, ctx);

  gemm_out<<<256, 256, 0, stream>>>(ctx, wo_h, b_o, out_f);
  ln_kernel<<<M_ / 4, 256, 0, stream>>>(out_f, q, ln_g, ln_b);
}

// Round 11
// 477.359 us; speedup vs baseline: 1.4187x; 1.0419x over previous
//
#include <hip/hip_runtime.h>

// MultiHeadAttention: B=4 S=2048 D=1024 H=16 DK=64
// outputs: [out (B,S,D) fp32 ; attn (B,H,S,S) fp32]
#define B_ 4
#define S_ 2048
#define D_ 1024
#define H_ 16
#define DK_ 64
#define M_ (B_ * S_) /* 8192 */

typedef __attribute__((ext_vector_type(8))) _Float16 f16x8;
typedef __attribute__((ext_vector_type(4))) _Float16 f16x4;
typedef __attribute__((ext_vector_type(4))) float f32x4;

#define QSCALE 0.18033688011113607f /* 0.125 * log2(e) */

__device__ __forceinline__ f32x4 mfma16(f16x8 a, f16x8 b, f32x4 c) {
  return __builtin_amdgcn_mfma_f32_16x16x32_f16(a, b, c, 0, 0, 0);
}

// async global->LDS, 16B per lane; LDS dest is wave-uniform base + lane*16
__device__ __forceinline__ void gl2lds(const _Float16* g, _Float16* l) {
  __builtin_amdgcn_global_load_lds(
      (const __attribute__((address_space(1))) void*)g,
      (__attribute__((address_space(3))) void*)l, 16, 0, 0);
}

// ---------------- fp32 -> f16 for the 4 weight matrices ----------------
#define NW8 (D_ * D_ / 8) /* 131072 = 1<<17 */
__global__ __launch_bounds__(256) void cvt_w(
    const float* __restrict__ wq, const float* __restrict__ wk,
    const float* __restrict__ wv, const float* __restrict__ wo,
    _Float16* __restrict__ wqh, _Float16* __restrict__ wkh,
    _Float16* __restrict__ wvh, _Float16* __restrict__ woh) {
  const int i = blockIdx.x * 256 + threadIdx.x;
  const int t = i >> 17;
  const int off = i & (NW8 - 1);
  const float* src = t == 0 ? wq : (t == 1 ? wk : (t == 2 ? wv : wo));
  _Float16* dst = t == 0 ? wqh : (t == 1 ? wkh : (t == 2 ? wvh : woh));
  const f32x4 a = *reinterpret_cast<const f32x4*>(&src[(size_t)off * 8]);
  const f32x4 b = *reinterpret_cast<const f32x4*>(&src[(size_t)off * 8 + 4]);
  f16x8 h;
  h[0] = (_Float16)a[0]; h[1] = (_Float16)a[1]; h[2] = (_Float16)a[2]; h[3] = (_Float16)a[3];
  h[4] = (_Float16)b[0]; h[5] = (_Float16)b[1]; h[6] = (_Float16)b[2]; h[7] = (_Float16)b[3];
  *reinterpret_cast<f16x8*>(&dst[(size_t)off * 8]) = h;
}

// -------- merged QKV projection, BM=128 x BN=256 (wave tile 64x128) --------
// X fp32 (inline cvt to f16 in A-staging), W f16 via gl2lds.
// third 0: Q -> f16 [B][S][D], *QSCALE   third 1: K -> f16 [B][S][D]
// third 2: V -> f16 Vt [b][h][dk][s]
__global__ __launch_bounds__(256, 2) void gemm_qkv(
    const float* __restrict__ Xq, const float* __restrict__ Xk, const float* __restrict__ Xv,
    const _Float16* __restrict__ Wq, const _Float16* __restrict__ Wk, const _Float16* __restrict__ Wv,
    const float* __restrict__ bq, const float* __restrict__ bk, const float* __restrict__ bv,
    _Float16* __restrict__ Qh, _Float16* __restrict__ Kh, _Float16* __restrict__ Vt) {
  __shared__ _Float16 As[128 * 72];  // A reg-staged fp32->f16, padded stride 72 (18 KB)
  __shared__ _Float16 Bs[256 * 64];  // B via gl2lds, linear (32 KB)
  const int third = blockIdx.x >> 8;
  const int bid = blockIdx.x & 255;
  const float* X = third == 0 ? Xq : (third == 1 ? Xk : Xv);
  const _Float16* Bw = third == 0 ? Wq : (third == 1 ? Wk : Wv);
  const float* bias = third == 0 ? bq : (third == 1 ? bk : bv);

  const int t = threadIdx.x;
  const int lane = t & 63;
  const int w = t >> 6;
  const int wr = w >> 1, wc = w & 1;       // wave tile: rows wr*64, cols wc*128
  const int l15 = lane & 15, g = lane >> 4;
  const int m0 = (bid & 63) * 128;
  const int n0 = (bid >> 6) * 256;

  f32x4 acc[4][8] = {};
  const int srow = lane >> 3;       // 0..7
  const int schk = (lane & 7) * 8;  // 16B chunk for gl2lds
  const int ar = t >> 4;            // 0..15 (A-stage row within group)
  const int ac = (t & 15) * 4;      // 0..60 (A-stage col)

  for (int kt = 0; kt < 16; ++kt) {
    const int k0 = kt * 64;
    // B: 256 rows x 64 k-cols, 8 wave-groups of 8 rows
#pragma unroll
    for (int u = 0; u < 8; ++u)
      gl2lds(&Bw[(size_t)(n0 + u * 32 + w * 8 + srow) * D_ + k0 + schk], &Bs[u * 2048 + w * 512]);
    // A: 128 rows x 64 k-cols fp32 -> f16, padded stride 72
#pragma unroll
    for (int rg = 0; rg < 8; ++rg) {
      const int r = rg * 16 + ar;
      const f32x4 vv = *reinterpret_cast<const f32x4*>(&X[(size_t)(m0 + r) * D_ + k0 + ac]);
      f16x4 hh;
      hh[0] = (_Float16)vv[0]; hh[1] = (_Float16)vv[1];
      hh[2] = (_Float16)vv[2]; hh[3] = (_Float16)vv[3];
      *reinterpret_cast<f16x4*>(&As[r * 72 + ac]) = hh;
    }
    __syncthreads();
#pragma unroll
    for (int kk = 0; kk < 2; ++kk) {
      f16x8 af[4], bfr[8];
#pragma unroll
      for (int m = 0; m < 4; ++m)
        af[m] = *reinterpret_cast<const f16x8*>(&As[(wr * 64 + m * 16 + l15) * 72 + kk * 32 + 8 * g]);
#pragma unroll
      for (int n = 0; n < 8; ++n)
        bfr[n] = *reinterpret_cast<const f16x8*>(&Bs[(wc * 128 + n * 16 + l15) * 64 + kk * 32 + 8 * g]);
#pragma unroll
      for (int m = 0; m < 4; ++m)
#pragma unroll
        for (int n = 0; n < 8; ++n)
          acc[m][n] = mfma16(af[m], bfr[n], acc[m][n]);
    }
    __syncthreads();
  }

  if (third < 2) {
    _Float16* Y = third == 0 ? Qh : Kh;
    const float scl = third == 0 ? QSCALE : 1.0f;
#pragma unroll
    for (int m = 0; m < 4; ++m)
#pragma unroll
      for (int n = 0; n < 8; ++n)
#pragma unroll
        for (int i = 0; i < 4; ++i) {
          const int R = m0 + wr * 64 + m * 16 + 4 * g + i;
          const int C = n0 + wc * 128 + n * 16 + l15;
          Y[(size_t)R * D_ + C] = (_Float16)((acc[m][n][i] + bias[C]) * scl);
        }
  } else {
#pragma unroll
    for (int m = 0; m < 4; ++m)
#pragma unroll
      for (int n = 0; n < 8; ++n) {
        const int R0 = m0 + wr * 64 + m * 16 + 4 * g;
        const int C = n0 + wc * 128 + n * 16 + l15;
        const int b = R0 >> 11, s0 = R0 & (S_ - 1);
        const int h = C >> 6, dk = C & (DK_ - 1);
        f16x4 hv;
#pragma unroll
        for (int i = 0; i < 4; ++i) hv[i] = (_Float16)(acc[m][n][i] + bias[C]);
        *reinterpret_cast<f16x4*>(&Vt[((size_t)((b * H_ + h) * DK_ + dk)) * S_ + s0]) = hv;
      }
  }
}

// ---------------- out GEMM (R7 128x128 version): out = ctx @ Wo^T + b (fp32) ----------------
__global__ __launch_bounds__(256) void gemm_out(const _Float16* __restrict__ A,
                                                const _Float16* __restrict__ Bw,
                                                const float* __restrict__ bias,
                                                float* __restrict__ out) {
  __shared__ _Float16 As[128 * 64];
  __shared__ _Float16 Bs[128 * 64];
  const int t = threadIdx.x;
  const int lane = t & 63;
  const int w = t >> 6;
  const int wr = w >> 1, wc = w & 1;
  const int l15 = lane & 15, g = lane >> 4;
  const int m0 = (blockIdx.x & 63) * 128;
  const int n0 = (blockIdx.x >> 6) * 128;

  f32x4 acc[4][4] = {};
  const int srow = lane >> 3;
  const int schk = (lane & 7) * 8;

  for (int kt = 0; kt < 16; ++kt) {
    const int k0 = kt * 64;
#pragma unroll
    for (int u = 0; u < 4; ++u) {
      const int r = u * 32 + w * 8 + srow;
      gl2lds(&A[(size_t)(m0 + r) * D_ + k0 + schk], &As[u * 2048 + w * 512]);
      gl2lds(&Bw[(size_t)(n0 + r) * D_ + k0 + schk], &Bs[u * 2048 + w * 512]);
    }
    __syncthreads();
#pragma unroll
    for (int kk = 0; kk < 2; ++kk) {
      f16x8 af[4], bfr[4];
#pragma unroll
      for (int m = 0; m < 4; ++m)
        af[m] = *reinterpret_cast<const f16x8*>(&As[(wr * 64 + m * 16 + l15) * 64 + kk * 32 + 8 * g]);
#pragma unroll
      for (int n = 0; n < 4; ++n)
        bfr[n] = *reinterpret_cast<const f16x8*>(&Bs[(wc * 64 + n * 16 + l15) * 64 + kk * 32 + 8 * g]);
#pragma unroll
      for (int m = 0; m < 4; ++m)
#pragma unroll
        for (int n = 0; n < 4; ++n)
          acc[m][n] = mfma16(af[m], bfr[n], acc[m][n]);
    }
    __syncthreads();
  }

#pragma unroll
  for (int m = 0; m < 4; ++m)
#pragma unroll
    for (int n = 0; n < 4; ++n)
#pragma unroll
      for (int i = 0; i < 4; ++i) {
        const int R = m0 + wr * 64 + m * 16 + 4 * g + i;
        const int C = n0 + wc * 64 + n * 16 + l15;
        out[(size_t)R * D_ + C] = acc[m][n][i] + bias[C];
      }
}

// ---------------- attention pass 1: row sums of exp2(scores) ----------------
// XCD-swizzled block mapping: each XCD owns 8 consecutive bh's -> K panels L2-resident.
__global__ __launch_bounds__(256) void attn_pass1(const _Float16* __restrict__ Qh,
                                                  const _Float16* __restrict__ Kh,
                                                  float* __restrict__ lbuf) {
  __shared__ float red[4][64];
  const int t = threadIdx.x;
  const int lane = t & 63;
  const int w = t >> 6;
  const int l15 = lane & 15, g = lane >> 4;
  // bijective XCD swizzle: grid 2048 = 8 x 256
  const int bid = (blockIdx.x & 7) * 256 + (blockIdx.x >> 3);
  const int qc = bid & 31;  // S_/64
  const int bh = bid >> 5;
  const int b = bh >> 4, h = bh & 15;
  const int q0 = qc * 64;
  const _Float16* Qp = Qh + (size_t)b * S_ * D_ + h * DK_;
  const _Float16* Kp = Kh + (size_t)b * S_ * D_ + h * DK_;

  f16x8 qa[4][2];
#pragma unroll
  for (int mr = 0; mr < 4; ++mr)
#pragma unroll
    for (int kk = 0; kk < 2; ++kk)
      qa[mr][kk] = *reinterpret_cast<const f16x8*>(&Qp[(size_t)(q0 + mr * 16 + l15) * D_ + kk * 32 + 8 * g]);

  float l[4][4] = {};
  const int cbeg = w * (S_ / 4), cend = cbeg + (S_ / 4);
  f16x8 kb0 = *reinterpret_cast<const f16x8*>(&Kp[(size_t)(cbeg + l15) * D_ + 8 * g]);
  f16x8 kb1 = *reinterpret_cast<const f16x8*>(&Kp[(size_t)(cbeg + l15) * D_ + 32 + 8 * g]);
  for (int c0 = cbeg; c0 < cend; c0 += 16) {
    const int cn = (c0 + 16 < cend) ? c0 + 16 : cbeg;  // prefetch next (wrap harmless)
    const f16x8 nb0 = *reinterpret_cast<const f16x8*>(&Kp[(size_t)(cn + l15) * D_ + 8 * g]);
    const f16x8 nb1 = *reinterpret_cast<const f16x8*>(&Kp[(size_t)(cn + l15) * D_ + 32 + 8 * g]);
#pragma unroll
    for (int mr = 0; mr < 4; ++mr) {
      f32x4 sc = {};
      sc = mfma16(qa[mr][0], kb0, sc);
      sc = mfma16(qa[mr][1], kb1, sc);
#pragma unroll
      for (int i = 0; i < 4; ++i) l[mr][i] += exp2f(sc[i]);
    }
    kb0 = nb0; kb1 = nb1;
  }
#pragma unroll
  for (int mask = 1; mask < 16; mask <<= 1)
#pragma unroll
    for (int mr = 0; mr < 4; ++mr)
#pragma unroll
      for (int i = 0; i < 4; ++i) l[mr][i] += __shfl_xor(l[mr][i], mask, 64);
  if (l15 == 0)
#pragma unroll
    for (int mr = 0; mr < 4; ++mr)
#pragma unroll
      for (int i = 0; i < 4; ++i) red[w][mr * 16 + 4 * g + i] = l[mr][i];
  __syncthreads();
  if (t < 64)
    lbuf[(size_t)bh * S_ + q0 + t] = red[0][t] + red[1][t] + red[2][t] + red[3][t];
}

// ------- pass 2: recompute scores, write normalized P (vectorized NT), ctx = P @ V -------
// XCD-swizzled block mapping: each XCD owns 8 consecutive bh's -> K/V panels L2-resident.
__global__ __launch_bounds__(256) void attn_pass2(const _Float16* __restrict__ Qh,
                                                  const _Float16* __restrict__ Kh,
                                                  const _Float16* __restrict__ Vt,
                                                  const float* __restrict__ lbuf,
                                                  float* __restrict__ attn,
                                                  _Float16* __restrict__ ctx) {
  __shared__ float Ps[4][32 * 36];  // per-wave 32x32 fp32 P tile, stride 36 (16B-aligned rows)
  const int t = threadIdx.x;
  const int lane = t & 63;
  const int w = t >> 6;
  const int l15 = lane & 15, g = lane >> 4;
  // bijective XCD swizzle: grid 1024 = 8 x 128
  const int bid = (blockIdx.x & 7) * 128 + (blockIdx.x >> 3);
  const int qc = bid & 15;  // S_/128
  const int bh = bid >> 4;
  const int b = bh >> 4, h = bh & 15;
  const int q0 = qc * 128 + w * 32;
  const _Float16* Qp = Qh + (size_t)b * S_ * D_ + h * DK_;
  const _Float16* Kp = Kh + (size_t)b * S_ * D_ + h * DK_;
  const _Float16* Vp = Vt + (size_t)bh * DK_ * S_;

  f16x8 qa[2][2];
#pragma unroll
  for (int mr = 0; mr < 2; ++mr)
#pragma unroll
    for (int kk = 0; kk < 2; ++kk)
      qa[mr][kk] = *reinterpret_cast<const f16x8*>(&Qp[(size_t)(q0 + mr * 16 + l15) * D_ + kk * 32 + 8 * g]);

  float il[2][4];
#pragma unroll
  for (int mr = 0; mr < 2; ++mr)
#pragma unroll
    for (int i = 0; i < 4; ++i)
      il[mr][i] = 1.0f / lbuf[(size_t)bh * S_ + q0 + mr * 16 + 4 * g + i];

  f32x4 accv[2][4] = {};
  float* Pw = Ps[w];
  const int sr = lane >> 3;        // 0..7  (store row group)
  const int sc4 = (lane & 7) * 4;  // 0..28 (store col chunk)

  // No barrier in this loop (per-wave LDS tile) -> unroll 2 lets the scheduler
  // overlap one tile's NT stores / LDS ops with the next tile's MFMA+exp.
#pragma unroll 2
  for (int c0 = 0; c0 < S_; c0 += 32) {
#pragma unroll
    for (int ct = 0; ct < 2; ++ct) {
      const f16x8 kb0 = *reinterpret_cast<const f16x8*>(&Kp[(size_t)(c0 + ct * 16 + l15) * D_ + 8 * g]);
      const f16x8 kb1 = *reinterpret_cast<const f16x8*>(&Kp[(size_t)(c0 + ct * 16 + l15) * D_ + 32 + 8 * g]);
#pragma unroll
      for (int mr = 0; mr < 2; ++mr) {
        f32x4 sc = {};
        sc = mfma16(qa[mr][0], kb0, sc);
        sc = mfma16(qa[mr][1], kb1, sc);
#pragma unroll
        for (int i = 0; i < 4; ++i)
          Pw[(mr * 16 + 4 * g + i) * 36 + ct * 16 + l15] = exp2f(sc[i]) * il[mr][i];
      }
    }
    // vectorized attn store: 32 rows x 32 cols, 128B-contiguous per row
#pragma unroll
    for (int j = 0; j < 4; ++j) {
      const int r = sr + 8 * j;
      const f32x4 pv = *reinterpret_cast<const f32x4*>(&Pw[r * 36 + sc4]);
      __builtin_nontemporal_store(pv,
          reinterpret_cast<f32x4*>(&attn[((size_t)bh * S_ + q0 + r) * S_ + c0 + sc4]));
    }
    // PV: re-fragment P from LDS (fp32 -> f16), B from Vt (contiguous along s)
#pragma unroll
    for (int mr = 0; mr < 2; ++mr) {
      const f32x4 p0 = *reinterpret_cast<const f32x4*>(&Pw[(mr * 16 + l15) * 36 + 8 * g]);
      const f32x4 p1 = *reinterpret_cast<const f32x4*>(&Pw[(mr * 16 + l15) * 36 + 8 * g + 4]);
      f16x8 pa;
#pragma unroll
      for (int j = 0; j < 4; ++j) { pa[j] = (_Float16)p0[j]; pa[4 + j] = (_Float16)p1[j]; }
#pragma unroll
      for (int n = 0; n < 4; ++n) {
        const f16x8 vb = *reinterpret_cast<const f16x8*>(&Vp[(size_t)(n * 16 + l15) * S_ + c0 + 8 * g]);
        accv[mr][n] = mfma16(pa, vb, accv[mr][n]);
      }
    }
  }
#pragma unroll
  for (int mr = 0; mr < 2; ++mr)
#pragma unroll
    for (int n = 0; n < 4; ++n)
#pragma unroll
      for (int i = 0; i < 4; ++i) {
        const int row = q0 + mr * 16 + 4 * g + i;
        ctx[((size_t)(b * S_ + row)) * D_ + h * DK_ + n * 16 + l15] = (_Float16)accv[mr][n][i];
      }
}

// ---------------- residual + LayerNorm: one row per wave, no LDS ----------------
__global__ __launch_bounds__(256) void ln_kernel(float* __restrict__ out,
                                                 const float* __restrict__ resid,
                                                 const float* __restrict__ gamma,
                                                 const float* __restrict__ beta) {
  const int t = threadIdx.x;
  const int lane = t & 63, w = t >> 6;
  const int row = blockIdx.x * 4 + w;
  const size_t rb = (size_t)row * D_;
  f32x4 x[4];
  float s = 0.f, s2 = 0.f;
#pragma unroll
  for (int c = 0; c < 4; ++c) {
    const int off = c * 256 + lane * 4;
    const f32x4 o = *reinterpret_cast<const f32x4*>(&out[rb + off]);
    const f32x4 r = *reinterpret_cast<const f32x4*>(&resid[rb + off]);
    x[c] = o + r;
#pragma unroll
    for (int j = 0; j < 4; ++j) { s += x[c][j]; s2 += x[c][j] * x[c][j]; }
  }
#pragma unroll
  for (int mask = 1; mask < 64; mask <<= 1) {
    s += __shfl_xor(s, mask, 64);
    s2 += __shfl_xor(s2, mask, 64);
  }
  const float mu = s * (1.0f / D_);
  const float var = s2 * (1.0f / D_) - mu * mu;
  const float rstd = rsqrtf(var + 1e-5f);
#pragma unroll
  for (int c = 0; c < 4; ++c) {
    const int off = c * 256 + lane * 4;
    const f32x4 gm = *reinterpret_cast<const f32x4*>(&gamma[off]);
    const f32x4 bt = *reinterpret_cast<const f32x4*>(&beta[off]);
    f32x4 y;
#pragma unroll
    for (int j = 0; j < 4; ++j) y[j] = (x[c][j] - mu) * rstd * gm[j] + bt[j];
    *reinterpret_cast<f32x4*>(&out[rb + off]) = y;
  }
}

extern "C" void kernel_launch(void* const* d_in, const int* in_sizes, int n_in,
                              void* d_out, int out_size, void* d_ws, size_t ws_size,
                              hipStream_t stream) {
  (void)in_sizes; (void)n_in; (void)out_size; (void)ws_size;
  const float* q    = (const float*)d_in[0];
  const float* k    = (const float*)d_in[1];
  const float* v    = (const float*)d_in[2];
  const float* w_q  = (const float*)d_in[3];
  const float* b_q  = (const float*)d_in[4];
  const float* w_k  = (const float*)d_in[5];
  const float* b_k  = (const float*)d_in[6];
  const float* w_v  = (const float*)d_in[7];
  const float* b_v  = (const float*)d_in[8];
  const float* w_o  = (const float*)d_in[9];
  const float* b_o  = (const float*)d_in[10];
  const float* ln_g = (const float*)d_in[11];
  const float* ln_b = (const float*)d_in[12];

  char* ws = (char*)d_ws;
  _Float16* wq_h = (_Float16*)(ws + ((size_t)0 << 20));
  _Float16* wk_h = (_Float16*)(ws + ((size_t)2 << 20));
  _Float16* wv_h = (_Float16*)(ws + ((size_t)4 << 20));
  _Float16* wo_h = (_Float16*)(ws + ((size_t)6 << 20));
  _Float16* Qh   = (_Float16*)(ws + ((size_t)8 << 20));   // [B][S][D], pre-scaled QSCALE
  _Float16* Kh   = (_Float16*)(ws + ((size_t)26 << 20));  // [B][S][D]
  _Float16* Vt   = (_Float16*)(ws + ((size_t)44 << 20));  // [B][H][DK][S]
  _Float16* ctx  = (_Float16*)(ws + ((size_t)62 << 20));  // [M][1024]
  float*    lbuf = (float*)(ws + ((size_t)80 << 20));     // [64][2048]

  float* out_f = (float*)d_out;
  float* attn_f = out_f + (size_t)M_ * D_;

  cvt_w<<<4 * NW8 / 256, 256, 0, stream>>>(w_q, w_k, w_v, w_o, wq_h, wk_h, wv_h, wo_h);

  gemm_qkv<<<768, 256, 0, stream>>>(q, k, v, wq_h, wk_h, wv_h, b_q, b_k, b_v, Qh, Kh, Vt);

  attn_pass1<<<B_ * H_ * (S_ / 64), 256, 0, stream>>>(Qh, Kh, lbuf);
  attn_pass2<<<B_ * H_ * (S_ / 128), 256, 0, stream>>>(Qh, Kh, Vt, lbuf, attn_f, ctx);

  gemm_out<<<512, 256, 0, stream>>>(ctx, wo_h, b_o, out_f);
  ln_kernel<<<M_ / 4, 256, 0, stream>>>(out_f, q, ln_g, ln_b);
}